// Round 6
// baseline (158.547 us; speedup 1.0000x reference)
//
#include <hip/hip_runtime.h>
#include <hip/hip_bf16.h>

// Problem constants
#define BATCH 8
#define SEQ   2048
#define DEMB  1024
#define HD    64
#define NROWS (BATCH * SEQ)   // 16384

typedef __attribute__((ext_vector_type(8))) short bf16x8;  // 8 bf16 in 4 VGPRs
typedef __attribute__((ext_vector_type(4))) float f32x4;

// fp32 -> bf16 round-to-nearest-even (bit pattern as short)
__device__ inline short f2b(float f) {
    unsigned u = __builtin_bit_cast(unsigned, f);
    unsigned r = (u + 0x7fffu + ((u >> 16) & 1u)) >> 16;
    return (short)r;
}

// ---------------------------------------------------------------------------
// Kernel 0: prep — Wt[n][d] = W(d,n) as bf16 (n: 0..63 Wq, 64..127 Wk, 128..191 Wv)
//           bias[192] fp32 concat
// ---------------------------------------------------------------------------
__global__ void prep_kernel(const float* __restrict__ Wq, const float* __restrict__ bq,
                            const float* __restrict__ Wk, const float* __restrict__ bk,
                            const float* __restrict__ Wv, const float* __restrict__ bv,
                            short* __restrict__ Wt, float* __restrict__ bias) {
    int idx = blockIdx.x * blockDim.x + threadIdx.x;   // 0 .. 192*1024-1
    if (idx < 192 * 1024) {
        int n = idx >> 10;
        int d = idx & 1023;
        const float* W = (n < 64) ? Wq : (n < 128) ? Wk : Wv;
        int nn = n & 63;
        Wt[idx] = f2b(W[(size_t)d * 64 + nn]);
    }
    if (idx < 192) {
        const float* bb = (idx < 64) ? bq : (idx < 128) ? bk : bv;
        bias[idx] = bb[idx & 63];
    }
}

// ---------------------------------------------------------------------------
// Kernel 1: fused QKV projection via MFMA bf16.
//   Grid: 1024 blocks x 256 threads (4 waves). Block = 16 rows; wave w covers
//   col fragments [3w, 3w+3) (48 cols). 4096 waves = 4 waves/SIMD for latency
//   hiding; the 4 waves of a block load identical x data (L1 broadcast).
//   A frag: x[row][k0 + lg*8 .. +8] (fp32 -> bf16)
//   B frag: Wt[n][k0 + lg*8 .. +8] (contiguous bf16)
//   Writes Q,K row-major bf16 [16384][64]; V transposed Vt[b][64][2048] bf16.
// ---------------------------------------------------------------------------
__global__ __launch_bounds__(256) void proj_kernel(const float* __restrict__ x,
        const short* __restrict__ Wt, const float* __restrict__ bias,
        short* __restrict__ Qo, short* __restrict__ Ko, short* __restrict__ Vto) {
    const int wid  = threadIdx.x >> 6;
    const int lane = threadIdx.x & 63;
    const int l15  = lane & 15;
    const int lg   = lane >> 4;
    const int t0   = blockIdx.x * 16;       // block's 16 rows
    const int row  = t0 + l15;
    const int nf0  = wid * 3;               // this wave's first col-fragment

    const float* xr  = x + (size_t)row * DEMB + lg * 8;
    const short* wp0 = Wt + (size_t)(nf0 * 16 + l15) * DEMB + lg * 8;

    f32x4 acc[3];
#pragma unroll
    for (int i = 0; i < 3; ++i) acc[i] = (f32x4){0.f, 0.f, 0.f, 0.f};

    for (int k0 = 0; k0 < DEMB; k0 += 32) {
        // A fragment: 8 consecutive fp32 -> bf16
        f32x4 xa = *(const f32x4*)(xr + k0);
        f32x4 xb = *(const f32x4*)(xr + k0 + 4);
        bf16x8 af;
        af[0] = f2b(xa[0]); af[1] = f2b(xa[1]); af[2] = f2b(xa[2]); af[3] = f2b(xa[3]);
        af[4] = f2b(xb[0]); af[5] = f2b(xb[1]); af[6] = f2b(xb[2]); af[7] = f2b(xb[3]);
        const short* wp = wp0 + k0;
#pragma unroll
        for (int i = 0; i < 3; ++i) {
            bf16x8 bfv = *(const bf16x8*)(wp + (size_t)i * 16 * DEMB);
            acc[i] = __builtin_amdgcn_mfma_f32_16x16x32_bf16(af, bfv, acc[i], 0, 0, 0);
        }
    }

    // Epilogue: +bias, write bf16. C/D layout: col = l15, row = lg*4 + j.
#pragma unroll
    for (int i = 0; i < 3; ++i) {
        int n = (nf0 + i) * 16 + l15;
        float bv_ = bias[n];
#pragma unroll
        for (int j = 0; j < 4; ++j) {
            int t = t0 + lg * 4 + j;
            short v = f2b(acc[i][j] + bv_);
            if (n < 64) {
                Qo[(size_t)t * HD + n] = v;
            } else if (n < 128) {
                Ko[(size_t)t * HD + (n - 64)] = v;
            } else {
                int b = t >> 11, tt = t & 2047, d = n - 128;
                Vto[((size_t)b * HD + d) * SEQ + tt] = v;
            }
        }
    }
}

// ---------------------------------------------------------------------------
// Kernel 2: causal flash attention, KVBLK = 64.
//   1024 waves total (256 blocks x 4 waves); wave = (batch b, 16 q-rows).
//   Work-balancing remap pairs chunk c with 127-c.
//   Per tile: 8 QK MFMAs + one softmax pass + 8 PV MFMAs. P transposed
//   through padded LDS ([72]-short rows -> ~2-way banks instead of 16-way).
// ---------------------------------------------------------------------------
__global__ __launch_bounds__(256) void attn_kernel(const short* __restrict__ Q,
        const short* __restrict__ K, const short* __restrict__ Vt,
        float* __restrict__ out) {
    __shared__ short plds[4][16][72];       // padded: 144B row stride

    const int wid  = threadIdx.x >> 6;
    const int lane = threadIdx.x & 63;
    const int l15  = lane & 15;
    const int lg   = lane >> 4;

    const int gw = blockIdx.x * 4 + wid;    // 0..1023
    const int b  = gw >> 7;
    const int c0 = gw & 127;
    const int c  = (c0 & 1) ? (127 - (c0 >> 1)) : (c0 >> 1);
    const int q0 = c * 16;                  // first q row (within batch)

    // Q fragments (held in registers for the whole kernel)
    const short* qbase = Q + ((size_t)(b * SEQ + q0 + l15)) * HD + lg * 8;
    bf16x8 qf0 = *(const bf16x8*)(qbase);
    bf16x8 qf1 = *(const bf16x8*)(qbase + 32);

    f32x4 o[4];
    float m[4], lsum[4];
#pragma unroll
    for (int df = 0; df < 4; ++df) o[df] = (f32x4){0.f, 0.f, 0.f, 0.f};
#pragma unroll
    for (int j = 0; j < 4; ++j) { m[j] = -1e30f; lsum[j] = 0.f; }

    const int ntile = (q0 + 16 + 63) >> 6;  // 64-wide kv tiles covering [0, q0+16)
    const short* kbb = K  + (size_t)b * SEQ * HD;
    const short* vbb = Vt + (size_t)b * HD * SEQ;

    for (int tile = 0; tile < ntile; ++tile) {
        const int kv0 = tile * 64;

        // ---- S = Q K^T (4 col-frags x 2 k-steps) ----
        f32x4 s[4];
#pragma unroll
        for (int nf = 0; nf < 4; ++nf) s[nf] = (f32x4){0.f, 0.f, 0.f, 0.f};
        __builtin_amdgcn_s_setprio(1);
#pragma unroll
        for (int nf = 0; nf < 4; ++nf) {
            const short* kp = kbb + (size_t)(kv0 + nf * 16 + l15) * HD + lg * 8;
            bf16x8 kf0 = *(const bf16x8*)kp;
            bf16x8 kf1 = *(const bf16x8*)(kp + 32);
            s[nf] = __builtin_amdgcn_mfma_f32_16x16x32_bf16(qf0, kf0, s[nf], 0, 0, 0);
            s[nf] = __builtin_amdgcn_mfma_f32_16x16x32_bf16(qf1, kf1, s[nf], 0, 0, 0);
        }
        __builtin_amdgcn_s_setprio(0);

        // ---- scale + causal mask ----
        float sv[4][4];
#pragma unroll
        for (int nf = 0; nf < 4; ++nf)
#pragma unroll
            for (int j = 0; j < 4; ++j) {
                int qr = q0 + lg * 4 + j;
                int kv = kv0 + nf * 16 + l15;
                float v = s[nf][j] * 0.125f;
                sv[nf][j] = (kv <= qr) ? v : -1e30f;
            }

        // ---- row max over the 64 kv of this tile ----
        float mt[4];
#pragma unroll
        for (int j = 0; j < 4; ++j)
            mt[j] = fmaxf(fmaxf(sv[0][j], sv[1][j]), fmaxf(sv[2][j], sv[3][j]));
#pragma unroll
        for (int sh = 1; sh < 16; sh <<= 1)
#pragma unroll
            for (int j = 0; j < 4; ++j) mt[j] = fmaxf(mt[j], __shfl_xor(mt[j], sh));

        // ---- online softmax update ----
        float p[4][4], rs[4];
#pragma unroll
        for (int j = 0; j < 4; ++j) {
            float mn = fmaxf(m[j], mt[j]);
            float sf = __expf(m[j] - mn);
            m[j] = mn;
            lsum[j] *= sf;
#pragma unroll
            for (int df = 0; df < 4; ++df) o[df][j] *= sf;
#pragma unroll
            for (int nf = 0; nf < 4; ++nf) p[nf][j] = __expf(sv[nf][j] - mn);
            rs[j] = (p[0][j] + p[1][j]) + (p[2][j] + p[3][j]);
        }
#pragma unroll
        for (int sh = 1; sh < 16; sh <<= 1)
#pragma unroll
            for (int j = 0; j < 4; ++j) rs[j] += __shfl_xor(rs[j], sh);
#pragma unroll
        for (int j = 0; j < 4; ++j) lsum[j] += rs[j];

        // ---- transpose P through LDS (per-wave buffer, no barrier needed) ----
#pragma unroll
        for (int nf = 0; nf < 4; ++nf)
#pragma unroll
            for (int j = 0; j < 4; ++j)
                plds[wid][lg * 4 + j][nf * 16 + l15] = f2b(p[nf][j]);

        bf16x8 pa0 = *(const bf16x8*)&plds[wid][l15][lg * 8];
        bf16x8 pa1 = *(const bf16x8*)&plds[wid][l15][32 + lg * 8];

        // ---- O += P V (4 d-frags x 2 k-steps) ----
        __builtin_amdgcn_s_setprio(1);
#pragma unroll
        for (int df = 0; df < 4; ++df) {
            const short* vp = vbb + (size_t)(df * 16 + l15) * SEQ + kv0 + lg * 8;
            bf16x8 vf0 = *(const bf16x8*)vp;
            bf16x8 vf1 = *(const bf16x8*)(vp + 32);
            o[df] = __builtin_amdgcn_mfma_f32_16x16x32_bf16(pa0, vf0, o[df], 0, 0, 0);
            o[df] = __builtin_amdgcn_mfma_f32_16x16x32_bf16(pa1, vf1, o[df], 0, 0, 0);
        }
        __builtin_amdgcn_s_setprio(0);
    }

    // ---- epilogue: out = O / l ----
#pragma unroll
    for (int df = 0; df < 4; ++df) {
        int d = df * 16 + l15;
#pragma unroll
        for (int j = 0; j < 4; ++j) {
            int t = q0 + lg * 4 + j;
            out[((size_t)(b * SEQ + t)) * HD + d] = o[df][j] / lsum[j];
        }
    }
}

// ---------------------------------------------------------------------------
extern "C" void kernel_launch(void* const* d_in, const int* in_sizes, int n_in,
                              void* d_out, int out_size, void* d_ws, size_t ws_size,
                              hipStream_t stream) {
    const float* x  = (const float*)d_in[0];
    const float* Wq = (const float*)d_in[1];
    const float* bq = (const float*)d_in[2];
    const float* Wk = (const float*)d_in[3];
    const float* bk = (const float*)d_in[4];
    const float* Wv = (const float*)d_in[5];
    const float* bv = (const float*)d_in[6];
    float* out = (float*)d_out;

    char* ws = (char*)d_ws;
    // Workspace layout (bytes):
    //   Wt   bf16 [192][1024]          @ 0        (393216)
    //   bias f32  [192]                @ 393216   (768)
    //   Q    bf16 [16384][64]          @ 394240   (2097152)
    //   K    bf16 [16384][64]          @ 2491392  (2097152)
    //   Vt   bf16 [8][64][2048]        @ 4588544  (2097152)
    short* Wt   = (short*)(ws);
    float* bias = (float*)(ws + 393216);
    short* Qb   = (short*)(ws + 394240);
    short* Kb   = (short*)(ws + 394240 + 2097152);
    short* Vtb  = (short*)(ws + 394240 + 2 * 2097152);

    hipLaunchKernelGGL(prep_kernel, dim3(768), dim3(256), 0, stream,
                       Wq, bq, Wk, bk, Wv, bv, Wt, bias);
    hipLaunchKernelGGL(proj_kernel, dim3(1024), dim3(256), 0, stream,
                       x, Wt, bias, Qb, Kb, Vtb);
    hipLaunchKernelGGL(attn_kernel, dim3(256), dim3(256), 0, stream,
                       Qb, Kb, Vtb, out);
}

// Round 8
// 100.679 us; speedup vs baseline: 1.5748x; 1.5748x over previous
//
#include <hip/hip_runtime.h>
#include <hip/hip_bf16.h>
#include <stdint.h>

// Problem constants
#define BATCH 8
#define SEQ   2048
#define DEMB  1024
#define HD    64
#define NROWS (BATCH * SEQ)   // 16384

typedef __attribute__((ext_vector_type(8))) short bf16x8;  // 8 bf16 in 4 VGPRs
typedef __attribute__((ext_vector_type(4))) short s16x4;   // 4 bf16 (8 B)
typedef __attribute__((ext_vector_type(4))) float f32x4;

// fp32 -> bf16 round-to-nearest-even (bit pattern as short)
__device__ inline short f2b(float f) {
    unsigned u = __builtin_bit_cast(unsigned, f);
    unsigned r = (u + 0x7fffu + ((u >> 16) & 1u)) >> 16;
    return (short)r;
}

// async global->LDS, 16 B per lane; dest = lds_base (wave-uniform) + lane*16
__device__ inline void gload_lds16(const void* g, void* l) {
    auto gp = reinterpret_cast<const __attribute__((address_space(1))) void*>(
        reinterpret_cast<uintptr_t>(g));
    auto lp = reinterpret_cast<__attribute__((address_space(3))) void*>(
        reinterpret_cast<uintptr_t>(l));
    __builtin_amdgcn_global_load_lds(gp, lp, 16, 0, 0);
}

// ---------------------------------------------------------------------------
// Kernel 0: prep — Wt[n][d] = W(d,n) as bf16 (n: 0..63 Wq, 64..127 Wk, 128..191 Wv)
//           bias[192] fp32 concat
// ---------------------------------------------------------------------------
__global__ void prep_kernel(const float* __restrict__ Wq, const float* __restrict__ bq,
                            const float* __restrict__ Wk, const float* __restrict__ bk,
                            const float* __restrict__ Wv, const float* __restrict__ bv,
                            short* __restrict__ Wt, float* __restrict__ bias) {
    int idx = blockIdx.x * blockDim.x + threadIdx.x;   // 0 .. 192*1024-1
    if (idx < 192 * 1024) {
        int n = idx >> 10;
        int d = idx & 1023;
        const float* W = (n < 64) ? Wq : (n < 128) ? Wk : Wv;
        int nn = n & 63;
        Wt[idx] = f2b(W[(size_t)d * 64 + nn]);
    }
    if (idx < 192) {
        const float* bb = (idx < 64) ? bq : (idx < 128) ? bk : bv;
        bias[idx] = bb[idx & 63];
    }
}

// ---------------------------------------------------------------------------
// Kernel 1: QKV projection — m97-style LDS-staged double-buffered MFMA GEMM.
//   Grid 256 blocks x 4 waves. BM=64, BN=192, BK=64. Wave w: rows w*16..+16,
//   all 192 cols (12 n-frags), 24 MFMA per k-step.
//   A (x fp32): reg-staged coalesced (16B/lane), f2b once, ds_write with
//     XOR-swizzle byte ^= (row&7)<<4 (issue-early / write-late, T14).
//   B (Wt bf16): global_load_lds with PRE-SWIZZLED global source (m173),
//     LDS linear => ds_read_b128 frag reads are ~2-way conflict-free.
// ---------------------------------------------------------------------------
__global__ __launch_bounds__(256) void proj_kernel(const float* __restrict__ x,
        const short* __restrict__ Wt, const float* __restrict__ bias,
        short* __restrict__ Qo, short* __restrict__ Ko, short* __restrict__ Vto) {
    __shared__ short lA[2][64 * 64];    //  8 KB per buf (64 rows x 128 B)
    __shared__ short lB[2][192 * 64];   // 24 KB per buf (192 rows x 128 B)

    const int tid  = threadIdx.x;
    const int wid  = tid >> 6;
    const int lane = tid & 63;
    const int l15  = lane & 15;
    const int lg   = lane >> 4;
    const int row0 = blockIdx.x * 64;

    // staging decomposition
    const int sar = tid >> 4;   // 0..15: row-in-group for A staging
    const int sac = tid & 15;   // 16B chunk within 64-float k-window
    const int bn  = tid >> 3;   // 0..31: B row within round
    const int bc  = tid & 7;    // 16B chunk within 128-B B row

    f32x4 areg[4];

    auto loadA = [&](int k0) {
#pragma unroll
        for (int p = 0; p < 4; ++p) {
            int r = p * 16 + sar;
            areg[p] = *(const f32x4*)(x + (size_t)(row0 + r) * DEMB + k0 + sac * 4);
        }
    };
    auto writeA = [&](int bb) {
        char* base = (char*)lA[bb];
#pragma unroll
        for (int p = 0; p < 4; ++p) {
            int r = p * 16 + sar;
            int byte = r * 128 + ((sac * 8) ^ ((r & 7) << 4));
            s16x4 v;
            v[0] = f2b(areg[p][0]); v[1] = f2b(areg[p][1]);
            v[2] = f2b(areg[p][2]); v[3] = f2b(areg[p][3]);
            *(s16x4*)(base + byte) = v;
        }
    };
    auto stageB = [&](int k0, int bb) {
        const char* wb = (const char*)Wt;
#pragma unroll
        for (int j = 0; j < 6; ++j) {
            int n = j * 32 + bn;
            const char* src = wb + (size_t)n * 2048 + k0 * 2 + ((bc * 16) ^ ((n & 7) << 4));
            short* dst = lB[bb] + (size_t)(j * 256 + wid * 64) * 8;  // + lane*16B by HW
            gload_lds16(src, dst);
        }
    };

    f32x4 acc[12];
#pragma unroll
    for (int i = 0; i < 12; ++i) acc[i] = (f32x4){0.f, 0.f, 0.f, 0.f};

    loadA(0);
    stageB(0, 0);
    writeA(0);
    __syncthreads();

    int buf = 0;
    for (int ks = 0; ks < 16; ++ks) {
        if (ks < 15) { loadA((ks + 1) * 64); stageB((ks + 1) * 64, buf ^ 1); }

        const char* aB = (const char*)lA[buf];
        const char* bB = (const char*)lB[buf];
        const int ar = wid * 16 + l15;
        const int as = (ar & 7) << 4;
        bf16x8 a0 = *(const bf16x8*)(aB + ar * 128 + ((lg * 16) ^ as));
        bf16x8 a1 = *(const bf16x8*)(aB + ar * 128 + ((lg * 16 + 64) ^ as));
#pragma unroll
        for (int nf = 0; nf < 12; ++nf) {
            int br = nf * 16 + l15;
            int bs = (br & 7) << 4;
            bf16x8 b0 = *(const bf16x8*)(bB + br * 128 + ((lg * 16) ^ bs));
            bf16x8 b1 = *(const bf16x8*)(bB + br * 128 + ((lg * 16 + 64) ^ bs));
            acc[nf] = __builtin_amdgcn_mfma_f32_16x16x32_bf16(a0, b0, acc[nf], 0, 0, 0);
            acc[nf] = __builtin_amdgcn_mfma_f32_16x16x32_bf16(a1, b1, acc[nf], 0, 0, 0);
        }

        if (ks < 15) writeA(buf ^ 1);
        __syncthreads();
        buf ^= 1;
    }

    // Epilogue: +bias, write bf16. C/D layout: col = l15, row = lg*4 + j.
    const int t0 = row0 + wid * 16;
#pragma unroll
    for (int nf = 0; nf < 12; ++nf) {
        int n = nf * 16 + l15;
        float bv_ = bias[n];
#pragma unroll
        for (int j = 0; j < 4; ++j) {
            int t = t0 + lg * 4 + j;
            short v = f2b(acc[nf][j] + bv_);
            if (n < 64) {
                Qo[(size_t)t * HD + n] = v;
            } else if (n < 128) {
                Ko[(size_t)t * HD + (n - 64)] = v;
            } else {
                int b = t >> 11, tt = t & 2047, d = n - 128;
                Vto[((size_t)b * HD + d) * SEQ + tt] = v;
            }
        }
    }
}

// ---------------------------------------------------------------------------
// Kernel 2: causal flash attention, split-KV x4.
//   Grid 1024 blocks x 4 waves. Block = (batch b, 16-row chunk c); wave wid
//   is KV-quarter qd: processes tiles t = qd, qd+4, ... (KVBLK=32, r3 body).
//   Writes UNNORMALIZED O + (m, l) partials; merge_kernel combines.
//   Running-max clamped at -1e20 so fully-masked rows can't emit exp(0)=1.
// ---------------------------------------------------------------------------
__global__ __launch_bounds__(256) void attn_kernel(const short* __restrict__ Q,
        const short* __restrict__ K, const short* __restrict__ Vt,
        float* __restrict__ Opart, float* __restrict__ mlbuf) {
    __shared__ short plds[4][16][40];   // pad 40 shorts: ~2-way banks on pa read

    const int wid  = threadIdx.x >> 6;
    const int lane = threadIdx.x & 63;
    const int l15  = lane & 15;
    const int lg   = lane >> 4;

    const int qd = wid;                 // KV quarter 0..3
    const int b  = blockIdx.x >> 7;
    const int c  = blockIdx.x & 127;
    const int q0 = c * 16;

    const short* qbase = Q + ((size_t)(b * SEQ + q0 + l15)) * HD + lg * 8;
    bf16x8 qf0 = *(const bf16x8*)(qbase);
    bf16x8 qf1 = *(const bf16x8*)(qbase + 32);

    f32x4 o[4];
    float m[4], lsum[4];
#pragma unroll
    for (int df = 0; df < 4; ++df) o[df] = (f32x4){0.f, 0.f, 0.f, 0.f};
#pragma unroll
    for (int j = 0; j < 4; ++j) { m[j] = -1e30f; lsum[j] = 0.f; }

    const int ntile = (q0 + 16 + 31) >> 5;
    const short* kbb = K  + (size_t)b * SEQ * HD;
    const short* vbb = Vt + (size_t)b * HD * SEQ;

    for (int tile = qd; tile < ntile; tile += 4) {
        const int kv0 = tile * 32;

        // ---- S = Q K^T ----
        f32x4 s[2] = {(f32x4){0.f,0.f,0.f,0.f}, (f32x4){0.f,0.f,0.f,0.f}};
#pragma unroll
        for (int nf = 0; nf < 2; ++nf) {
            const short* kp = kbb + (size_t)(kv0 + nf * 16 + l15) * HD + lg * 8;
            bf16x8 kf0 = *(const bf16x8*)kp;
            bf16x8 kf1 = *(const bf16x8*)(kp + 32);
            s[nf] = __builtin_amdgcn_mfma_f32_16x16x32_bf16(qf0, kf0, s[nf], 0, 0, 0);
            s[nf] = __builtin_amdgcn_mfma_f32_16x16x32_bf16(qf1, kf1, s[nf], 0, 0, 0);
        }

        // ---- scale + causal mask ----
        float sv[2][4];
#pragma unroll
        for (int nf = 0; nf < 2; ++nf)
#pragma unroll
            for (int j = 0; j < 4; ++j) {
                int qr = q0 + lg * 4 + j;
                int kv = kv0 + nf * 16 + l15;
                float v = s[nf][j] * 0.125f;
                sv[nf][j] = (kv <= qr) ? v : -1e30f;
            }

        // ---- row max over the 32 kv of this tile ----
        float mt[4];
#pragma unroll
        for (int j = 0; j < 4; ++j) mt[j] = fmaxf(sv[0][j], sv[1][j]);
#pragma unroll
        for (int sh = 1; sh < 16; sh <<= 1)
#pragma unroll
            for (int j = 0; j < 4; ++j) mt[j] = fmaxf(mt[j], __shfl_xor(mt[j], sh));

        // ---- online softmax update (clamped: fully-masked tiles stay zero) ----
        float p[2][4], rs[4];
#pragma unroll
        for (int j = 0; j < 4; ++j) {
            float mn = fmaxf(fmaxf(m[j], mt[j]), -1e20f);
            float sf = __expf(m[j] - mn);
            m[j] = mn;
            lsum[j] *= sf;
#pragma unroll
            for (int df = 0; df < 4; ++df) o[df][j] *= sf;
            p[0][j] = __expf(sv[0][j] - mn);
            p[1][j] = __expf(sv[1][j] - mn);
            rs[j] = p[0][j] + p[1][j];
        }
#pragma unroll
        for (int sh = 1; sh < 16; sh <<= 1)
#pragma unroll
            for (int j = 0; j < 4; ++j) rs[j] += __shfl_xor(rs[j], sh);
#pragma unroll
        for (int j = 0; j < 4; ++j) lsum[j] += rs[j];

        // ---- transpose P through LDS (per-wave buffer, no barrier needed) ----
#pragma unroll
        for (int nf = 0; nf < 2; ++nf)
#pragma unroll
            for (int j = 0; j < 4; ++j)
                plds[wid][lg * 4 + j][nf * 16 + l15] = f2b(p[nf][j]);

        bf16x8 pa = *(const bf16x8*)&plds[wid][l15][lg * 8];

        // ---- O += P V ----
#pragma unroll
        for (int df = 0; df < 4; ++df) {
            const short* vp = vbb + (size_t)(df * 16 + l15) * SEQ + kv0 + lg * 8;
            bf16x8 vf = *(const bf16x8*)vp;
            o[df] = __builtin_amdgcn_mfma_f32_16x16x32_bf16(pa, vf, o[df], 0, 0, 0);
        }
    }

    // ---- epilogue: write unnormalized partials ----
#pragma unroll
    for (int df = 0; df < 4; ++df) {
        int d = df * 16 + l15;
#pragma unroll
        for (int j = 0; j < 4; ++j) {
            size_t R = (size_t)b * SEQ + q0 + lg * 4 + j;
            Opart[((size_t)qd * NROWS + R) * HD + d] = o[df][j];
        }
    }
    if (l15 == 0) {
#pragma unroll
        for (int j = 0; j < 4; ++j) {
            size_t R = (size_t)b * SEQ + q0 + lg * 4 + j;
            mlbuf[((size_t)qd * NROWS + R) * 2 + 0] = m[j];
            mlbuf[((size_t)qd * NROWS + R) * 2 + 1] = lsum[j];
        }
    }
}

// ---------------------------------------------------------------------------
// Kernel 3: merge 4 KV-split partials -> normalized output.
// ---------------------------------------------------------------------------
__global__ __launch_bounds__(256) void merge_kernel(const float* __restrict__ Opart,
        const float* __restrict__ mlbuf, float* __restrict__ out) {
    int tg = blockIdx.x * 256 + threadIdx.x;   // 0 .. 262143
    int rr = tg >> 4;
    int fc = tg & 15;

    float mv[4], lv[4];
    float M = -3e38f;
#pragma unroll
    for (int i = 0; i < 4; ++i) {
        mv[i] = mlbuf[((size_t)i * NROWS + rr) * 2 + 0];
        lv[i] = mlbuf[((size_t)i * NROWS + rr) * 2 + 1];
        M = fmaxf(M, mv[i]);
    }
    float L = 0.f;
    f32x4 acc = (f32x4){0.f, 0.f, 0.f, 0.f};
#pragma unroll
    for (int i = 0; i < 4; ++i) {
        float w = __expf(mv[i] - M);
        L += lv[i] * w;
        f32x4 v = *(const f32x4*)(Opart + ((size_t)i * NROWS + rr) * HD + fc * 4);
        acc += v * w;
    }
    f32x4 r = acc / L;
    *(f32x4*)(out + (size_t)rr * HD + fc * 4) = r;
}

// ---------------------------------------------------------------------------
extern "C" void kernel_launch(void* const* d_in, const int* in_sizes, int n_in,
                              void* d_out, int out_size, void* d_ws, size_t ws_size,
                              hipStream_t stream) {
    const float* x  = (const float*)d_in[0];
    const float* Wq = (const float*)d_in[1];
    const float* bq = (const float*)d_in[2];
    const float* Wk = (const float*)d_in[3];
    const float* bk = (const float*)d_in[4];
    const float* Wv = (const float*)d_in[5];
    const float* bv = (const float*)d_in[6];
    float* out = (float*)d_out;

    char* ws = (char*)d_ws;
    // Workspace layout (bytes):
    //   Wt    bf16 [192][1024]        @ 0         (393216)
    //   bias  f32  [192]              @ 393216    (768, pad to 394240)
    //   Q     bf16 [16384][64]        @ 394240    (2097152)
    //   K     bf16 [16384][64]        @ 2491392   (2097152)
    //   Vt    bf16 [8][64][2048]      @ 4588544   (2097152)
    //   Opart f32  [4][16384][64]     @ 6685696   (16777216)
    //   ml    f32  [4][16384][2]      @ 23462912  (524288)   end 23987200
    short* Wt   = (short*)(ws);
    float* bias = (float*)(ws + 393216);
    short* Qb   = (short*)(ws + 394240);
    short* Kb   = (short*)(ws + 394240 + 2097152);
    short* Vtb  = (short*)(ws + 394240 + 2 * 2097152);
    float* Op   = (float*)(ws + 6685696);
    float* ml   = (float*)(ws + 23462912);

    hipLaunchKernelGGL(prep_kernel, dim3(768), dim3(256), 0, stream,
                       Wq, bq, Wk, bk, Wv, bv, Wt, bias);
    hipLaunchKernelGGL(proj_kernel, dim3(256), dim3(256), 0, stream,
                       x, Wt, bias, Qb, Kb, Vtb);
    hipLaunchKernelGGL(attn_kernel, dim3(1024), dim3(256), 0, stream,
                       Qb, Kb, Vtb, Op, ml);
    hipLaunchKernelGGL(merge_kernel, dim3(1024), dim3(256), 0, stream,
                       Op, ml, out);
}

// Round 10
// 74.226 us; speedup vs baseline: 2.1360x; 1.3564x over previous
//
#include <hip/hip_runtime.h>
#include <hip/hip_bf16.h>
#include <stdint.h>

// Problem constants
#define BATCH 8
#define SEQ   2048
#define DEMB  1024
#define HD    64
#define NROWS (BATCH * SEQ)   // 16384

typedef __attribute__((ext_vector_type(8))) short bf16x8;  // 8 bf16 in 4 VGPRs
typedef __attribute__((ext_vector_type(4))) short s16x4;   // 4 bf16 (8 B)
typedef __attribute__((ext_vector_type(4))) float f32x4;

// fp32 -> bf16 round-to-nearest-even (bit pattern as short)
__device__ inline short f2b(float f) {
    unsigned u = __builtin_bit_cast(unsigned, f);
    unsigned r = (u + 0x7fffu + ((u >> 16) & 1u)) >> 16;
    return (short)r;
}

// async global->LDS, 16 B per lane; dest = lds_base (wave-uniform) + lane*16
__device__ inline void gload_lds16(const void* g, void* l) {
    auto gp = reinterpret_cast<const __attribute__((address_space(1))) void*>(
        reinterpret_cast<uintptr_t>(g));
    auto lp = reinterpret_cast<__attribute__((address_space(3))) void*>(
        reinterpret_cast<uintptr_t>(l));
    __builtin_amdgcn_global_load_lds(gp, lp, 16, 0, 0);
}

// ---------------------------------------------------------------------------
// Kernel 0: prep — Wt[n][d] = W(d,n) as bf16 (n: 0..63 Wq, 64..127 Wk, 128..191 Wv)
//           bias[192] fp32 concat
// ---------------------------------------------------------------------------
__global__ void prep_kernel(const float* __restrict__ Wq, const float* __restrict__ bq,
                            const float* __restrict__ Wk, const float* __restrict__ bk,
                            const float* __restrict__ Wv, const float* __restrict__ bv,
                            short* __restrict__ Wt, float* __restrict__ bias) {
    int idx = blockIdx.x * blockDim.x + threadIdx.x;   // 0 .. 192*1024-1
    if (idx < 192 * 1024) {
        int n = idx >> 10;
        int d = idx & 1023;
        const float* W = (n < 64) ? Wq : (n < 128) ? Wk : Wv;
        int nn = n & 63;
        Wt[idx] = f2b(W[(size_t)d * 64 + nn]);
    }
    if (idx < 192) {
        const float* bb = (idx < 64) ? bq : (idx < 128) ? bk : bv;
        bias[idx] = bb[idx & 63];
    }
}

// ---------------------------------------------------------------------------
// Kernel 1: QKV projection — LDS-staged double-buffered MFMA GEMM (unchanged r7).
// ---------------------------------------------------------------------------
__global__ __launch_bounds__(256) void proj_kernel(const float* __restrict__ x,
        const short* __restrict__ Wt, const float* __restrict__ bias,
        short* __restrict__ Qo, short* __restrict__ Ko, short* __restrict__ Vto) {
    __shared__ short lA[2][64 * 64];    //  8 KB per buf (64 rows x 128 B)
    __shared__ short lB[2][192 * 64];   // 24 KB per buf (192 rows x 128 B)

    const int tid  = threadIdx.x;
    const int wid  = tid >> 6;
    const int lane = tid & 63;
    const int l15  = lane & 15;
    const int lg   = lane >> 4;
    const int row0 = blockIdx.x * 64;

    const int sar = tid >> 4;   // 0..15: row-in-group for A staging
    const int sac = tid & 15;   // 16B chunk within 64-float k-window
    const int bn  = tid >> 3;   // 0..31: B row within round
    const int bc  = tid & 7;    // 16B chunk within 128-B B row

    f32x4 areg[4];

    auto loadA = [&](int k0) {
#pragma unroll
        for (int p = 0; p < 4; ++p) {
            int r = p * 16 + sar;
            areg[p] = *(const f32x4*)(x + (size_t)(row0 + r) * DEMB + k0 + sac * 4);
        }
    };
    auto writeA = [&](int bb) {
        char* base = (char*)lA[bb];
#pragma unroll
        for (int p = 0; p < 4; ++p) {
            int r = p * 16 + sar;
            int byte = r * 128 + ((sac * 8) ^ ((r & 7) << 4));
            s16x4 v;
            v[0] = f2b(areg[p][0]); v[1] = f2b(areg[p][1]);
            v[2] = f2b(areg[p][2]); v[3] = f2b(areg[p][3]);
            *(s16x4*)(base + byte) = v;
        }
    };
    auto stageB = [&](int k0, int bb) {
        const char* wb = (const char*)Wt;
#pragma unroll
        for (int j = 0; j < 6; ++j) {
            int n = j * 32 + bn;
            const char* src = wb + (size_t)n * 2048 + k0 * 2 + ((bc * 16) ^ ((n & 7) << 4));
            short* dst = lB[bb] + (size_t)(j * 256 + wid * 64) * 8;  // + lane*16B by HW
            gload_lds16(src, dst);
        }
    };

    f32x4 acc[12];
#pragma unroll
    for (int i = 0; i < 12; ++i) acc[i] = (f32x4){0.f, 0.f, 0.f, 0.f};

    loadA(0);
    stageB(0, 0);
    writeA(0);
    __syncthreads();

    int buf = 0;
    for (int ks = 0; ks < 16; ++ks) {
        if (ks < 15) { loadA((ks + 1) * 64); stageB((ks + 1) * 64, buf ^ 1); }

        const char* aB = (const char*)lA[buf];
        const char* bB = (const char*)lB[buf];
        const int ar = wid * 16 + l15;
        const int as = (ar & 7) << 4;
        bf16x8 a0 = *(const bf16x8*)(aB + ar * 128 + ((lg * 16) ^ as));
        bf16x8 a1 = *(const bf16x8*)(aB + ar * 128 + ((lg * 16 + 64) ^ as));
#pragma unroll
        for (int nf = 0; nf < 12; ++nf) {
            int br = nf * 16 + l15;
            int bs = (br & 7) << 4;
            bf16x8 b0 = *(const bf16x8*)(bB + br * 128 + ((lg * 16) ^ bs));
            bf16x8 b1 = *(const bf16x8*)(bB + br * 128 + ((lg * 16 + 64) ^ bs));
            acc[nf] = __builtin_amdgcn_mfma_f32_16x16x32_bf16(a0, b0, acc[nf], 0, 0, 0);
            acc[nf] = __builtin_amdgcn_mfma_f32_16x16x32_bf16(a1, b1, acc[nf], 0, 0, 0);
        }

        if (ks < 15) writeA(buf ^ 1);
        __syncthreads();
        buf ^= 1;
    }

    const int t0 = row0 + wid * 16;
#pragma unroll
    for (int nf = 0; nf < 12; ++nf) {
        int n = nf * 16 + l15;
        float bv_ = bias[n];
#pragma unroll
        for (int j = 0; j < 4; ++j) {
            int t = t0 + lg * 4 + j;
            short v = f2b(acc[nf][j] + bv_);
            if (n < 64) {
                Qo[(size_t)t * HD + n] = v;
            } else if (n < 128) {
                Ko[(size_t)t * HD + (n - 64)] = v;
            } else {
                int b = t >> 11, tt = t & 2047, d = n - 128;
                Vto[((size_t)b * HD + d) * SEQ + tt] = v;
            }
        }
    }
}

// ---------------------------------------------------------------------------
// Kernel 2: causal flash attention — LDS-staged K/V shared by 4 waves,
//   split-KV x4, KVBLK=64, double-buffered.
//   Grid: 8 b x 32 qg x 4 split = 1024 blocks x 4 waves.
//   Block = (b, 64 q-rows [g*64..+64), KV quarter). Wave wid owns 16 q-rows.
//   K tile [64][128B] and V tile [64][128B] staged via global_load_lds with
//   pre-swizzled source (byte ^= (row&7)<<4); ds_read_b128 at b128 floor.
//   P-transpose buffer is [16][72] per wave (KVBLK=64 needs 64 cols + pad;
//   r9's [40] overflowed -> corrupted P. 144B row stride => ~2-way banks).
//   Work-balance remap g <-> 31-g. Unnormalized partials + (m,l) -> merge.
// ---------------------------------------------------------------------------
__global__ __launch_bounds__(256, 4) void attn_kernel(const short* __restrict__ Q,
        const short* __restrict__ K, const short* __restrict__ Vt,
        float* __restrict__ Opart, float* __restrict__ mlbuf) {
    __shared__ short lK[2][64 * 64];    // 8 KB per buf
    __shared__ short lV[2][64 * 64];    // 8 KB per buf
    __shared__ short plds[4][16][72];   // per-wave P transpose (KVBLK=64 + pad)

    const int tid  = threadIdx.x;
    const int wid  = tid >> 6;
    const int lane = tid & 63;
    const int l15  = lane & 15;
    const int lg   = lane >> 4;

    const int split = blockIdx.x & 3;
    const int g0    = (blockIdx.x >> 2) & 31;
    const int b     = blockIdx.x >> 7;
    const int g     = (g0 & 1) ? (31 - (g0 >> 1)) : (g0 >> 1);
    const int q0    = g * 64 + wid * 16;      // this wave's first q row
    const int ntile = g + 1;                  // 64-wide kv tiles for this block

    const short* kbb = K  + (size_t)b * SEQ * HD;
    const short* vbb = Vt + (size_t)b * HD * SEQ;

    // staging lane decomposition: 8 rows x 8 chunks(16B) per issue
    const int srow = lane >> 3;
    const int schk = lane & 7;

    auto stageKV = [&](int kv0, int bb) {
#pragma unroll
        for (int i = 0; i < 2; ++i) {
            int rbase = wid * 16 + i * 8;
            int row   = rbase + srow;
            int swz   = (schk * 16) ^ ((row & 7) << 4);
            const char* ksrc = (const char*)(kbb + (size_t)(kv0 + row) * HD) + swz;
            const char* vsrc = (const char*)(vbb + (size_t)row * SEQ + kv0) + swz;
            gload_lds16(ksrc, &lK[bb][rbase * 64]);
            gload_lds16(vsrc, &lV[bb][rbase * 64]);
        }
    };

    // Q fragments (registers, whole kernel)
    const short* qbase = Q + ((size_t)(b * SEQ + q0 + l15)) * HD + lg * 8;
    bf16x8 qf0 = *(const bf16x8*)(qbase);
    bf16x8 qf1 = *(const bf16x8*)(qbase + 32);

    f32x4 o[4];
    float m[4], lsum[4];
#pragma unroll
    for (int df = 0; df < 4; ++df) o[df] = (f32x4){0.f, 0.f, 0.f, 0.f};
#pragma unroll
    for (int j = 0; j < 4; ++j) { m[j] = -1e30f; lsum[j] = 0.f; }

    int t = split;
    if (t < ntile) stageKV(t * 64, 0);
    __syncthreads();   // vmcnt(0) drained before barrier => staging visible

    int buf = 0;
    for (; t < ntile; t += 4) {
        if (t + 4 < ntile) stageKV((t + 4) * 64, buf ^ 1);

        const int kv0 = t * 64;
        const char* kB = (const char*)lK[buf];
        const char* vB = (const char*)lV[buf];

        // ---- S = Q K^T (4 col-frags x 2 k-steps) ----
        f32x4 s[4];
#pragma unroll
        for (int nf = 0; nf < 4; ++nf) s[nf] = (f32x4){0.f, 0.f, 0.f, 0.f};
#pragma unroll
        for (int nf = 0; nf < 4; ++nf) {
            int br = nf * 16 + l15;
            int bs = (br & 7) << 4;
            bf16x8 kf0 = *(const bf16x8*)(kB + br * 128 + ((lg * 16) ^ bs));
            bf16x8 kf1 = *(const bf16x8*)(kB + br * 128 + ((lg * 16 + 64) ^ bs));
            s[nf] = __builtin_amdgcn_mfma_f32_16x16x32_bf16(qf0, kf0, s[nf], 0, 0, 0);
            s[nf] = __builtin_amdgcn_mfma_f32_16x16x32_bf16(qf1, kf1, s[nf], 0, 0, 0);
        }

        // ---- scale + causal mask ----
        float sv[4][4];
#pragma unroll
        for (int nf = 0; nf < 4; ++nf)
#pragma unroll
            for (int j = 0; j < 4; ++j) {
                int qr = q0 + lg * 4 + j;
                int kv = kv0 + nf * 16 + l15;
                float v = s[nf][j] * 0.125f;
                sv[nf][j] = (kv <= qr) ? v : -1e30f;
            }

        // ---- row max over the 64 kv of this tile ----
        float mt[4];
#pragma unroll
        for (int j = 0; j < 4; ++j)
            mt[j] = fmaxf(fmaxf(sv[0][j], sv[1][j]), fmaxf(sv[2][j], sv[3][j]));
#pragma unroll
        for (int sh = 1; sh < 16; sh <<= 1)
#pragma unroll
            for (int j = 0; j < 4; ++j) mt[j] = fmaxf(mt[j], __shfl_xor(mt[j], sh));

        // ---- online softmax update (clamped) ----
        float p[4][4], rs[4];
#pragma unroll
        for (int j = 0; j < 4; ++j) {
            float mn = fmaxf(fmaxf(m[j], mt[j]), -1e20f);
            float sf = __expf(m[j] - mn);
            m[j] = mn;
            lsum[j] *= sf;
#pragma unroll
            for (int df = 0; df < 4; ++df) o[df][j] *= sf;
#pragma unroll
            for (int nf = 0; nf < 4; ++nf) p[nf][j] = __expf(sv[nf][j] - mn);
            rs[j] = (p[0][j] + p[1][j]) + (p[2][j] + p[3][j]);
        }
#pragma unroll
        for (int sh = 1; sh < 16; sh <<= 1)
#pragma unroll
            for (int j = 0; j < 4; ++j) rs[j] += __shfl_xor(rs[j], sh);
#pragma unroll
        for (int j = 0; j < 4; ++j) lsum[j] += rs[j];

        // ---- transpose P through LDS (per-wave buffer) ----
#pragma unroll
        for (int nf = 0; nf < 4; ++nf)
#pragma unroll
            for (int j = 0; j < 4; ++j)
                plds[wid][lg * 4 + j][nf * 16 + l15] = f2b(p[nf][j]);

        bf16x8 pa0 = *(const bf16x8*)&plds[wid][l15][lg * 8];
        bf16x8 pa1 = *(const bf16x8*)&plds[wid][l15][32 + lg * 8];

        // ---- O += P V (4 d-frags x 2 k-steps) ----
#pragma unroll
        for (int df = 0; df < 4; ++df) {
            int dr = df * 16 + l15;
            int ds = (dr & 7) << 4;
            bf16x8 vf0 = *(const bf16x8*)(vB + dr * 128 + ((lg * 16) ^ ds));
            bf16x8 vf1 = *(const bf16x8*)(vB + dr * 128 + ((lg * 16 + 64) ^ ds));
            o[df] = __builtin_amdgcn_mfma_f32_16x16x32_bf16(pa0, vf0, o[df], 0, 0, 0);
            o[df] = __builtin_amdgcn_mfma_f32_16x16x32_bf16(pa1, vf1, o[df], 0, 0, 0);
        }

        __syncthreads();   // all waves done with buf; next staging completed
        buf ^= 1;
    }

    // ---- epilogue: write unnormalized partials ----
#pragma unroll
    for (int df = 0; df < 4; ++df) {
        int d = df * 16 + l15;
#pragma unroll
        for (int j = 0; j < 4; ++j) {
            size_t R = (size_t)b * SEQ + q0 + lg * 4 + j;
            Opart[((size_t)split * NROWS + R) * HD + d] = o[df][j];
        }
    }
    if (l15 == 0) {
#pragma unroll
        for (int j = 0; j < 4; ++j) {
            size_t R = (size_t)b * SEQ + q0 + lg * 4 + j;
            mlbuf[((size_t)split * NROWS + R) * 2 + 0] = m[j];
            mlbuf[((size_t)split * NROWS + R) * 2 + 1] = lsum[j];
        }
    }
}

// ---------------------------------------------------------------------------
// Kernel 3: merge 4 KV-split partials -> normalized output.
// ---------------------------------------------------------------------------
__global__ __launch_bounds__(256) void merge_kernel(const float* __restrict__ Opart,
        const float* __restrict__ mlbuf, float* __restrict__ out) {
    int tg = blockIdx.x * 256 + threadIdx.x;   // 0 .. 262143
    int rr = tg >> 4;
    int fc = tg & 15;

    float mv[4], lv[4];
    float M = -3e38f;
#pragma unroll
    for (int i = 0; i < 4; ++i) {
        mv[i] = mlbuf[((size_t)i * NROWS + rr) * 2 + 0];
        lv[i] = mlbuf[((size_t)i * NROWS + rr) * 2 + 1];
        M = fmaxf(M, mv[i]);
    }
    float L = 0.f;
    f32x4 acc = (f32x4){0.f, 0.f, 0.f, 0.f};
#pragma unroll
    for (int i = 0; i < 4; ++i) {
        float w = __expf(mv[i] - M);
        L += lv[i] * w;
        f32x4 v = *(const f32x4*)(Opart + ((size_t)i * NROWS + rr) * HD + fc * 4);
        acc += v * w;
    }
    f32x4 r = acc / L;
    *(f32x4*)(out + (size_t)rr * HD + fc * 4) = r;
}

// ---------------------------------------------------------------------------
extern "C" void kernel_launch(void* const* d_in, const int* in_sizes, int n_in,
                              void* d_out, int out_size, void* d_ws, size_t ws_size,
                              hipStream_t stream) {
    const float* x  = (const float*)d_in[0];
    const float* Wq = (const float*)d_in[1];
    const float* bq = (const float*)d_in[2];
    const float* Wk = (const float*)d_in[3];
    const float* bk = (const float*)d_in[4];
    const float* Wv = (const float*)d_in[5];
    const float* bv = (const float*)d_in[6];
    float* out = (float*)d_out;

    char* ws = (char*)d_ws;
    // Workspace layout (bytes):
    //   Wt    bf16 [192][1024]        @ 0         (393216)
    //   bias  f32  [192]              @ 393216    (768, pad to 394240)
    //   Q     bf16 [16384][64]        @ 394240    (2097152)
    //   K     bf16 [16384][64]        @ 2491392   (2097152)
    //   Vt    bf16 [8][64][2048]      @ 4588544   (2097152)
    //   Opart f32  [4][16384][64]     @ 6685696   (16777216)
    //   ml    f32  [4][16384][2]      @ 23462912  (524288)   end 23987200
    short* Wt   = (short*)(ws);
    float* bias = (float*)(ws + 393216);
    short* Qb   = (short*)(ws + 394240);
    short* Kb   = (short*)(ws + 394240 + 2097152);
    short* Vtb  = (short*)(ws + 394240 + 2 * 2097152);
    float* Op   = (float*)(ws + 6685696);
    float* ml   = (float*)(ws + 23462912);

    hipLaunchKernelGGL(prep_kernel, dim3(768), dim3(256), 0, stream,
                       Wq, bq, Wk, bk, Wv, bv, Wt, bias);
    hipLaunchKernelGGL(proj_kernel, dim3(256), dim3(256), 0, stream,
                       x, Wt, bias, Qb, Kb, Vtb);
    hipLaunchKernelGGL(attn_kernel, dim3(1024), dim3(256), 0, stream,
                       Qb, Kb, Vtb, Op, ml);
    hipLaunchKernelGGL(merge_kernel, dim3(1024), dim3(256), 0, stream,
                       Op, ml, out);
}

// Round 11
// 69.167 us; speedup vs baseline: 2.2922x; 1.0731x over previous
//
#include <hip/hip_runtime.h>
#include <hip/hip_bf16.h>
#include <stdint.h>

// Problem constants
#define BATCH 8
#define SEQ   2048
#define DEMB  1024
#define HD    64
#define NROWS (BATCH * SEQ)   // 16384

typedef __attribute__((ext_vector_type(8))) short bf16x8;  // 8 bf16 in 4 VGPRs
typedef __attribute__((ext_vector_type(4))) short s16x4;   // 4 bf16 (8 B)
typedef __attribute__((ext_vector_type(4))) float f32x4;

// fp32 -> bf16 round-to-nearest-even (bit pattern as short)
__device__ inline short f2b(float f) {
    unsigned u = __builtin_bit_cast(unsigned, f);
    unsigned r = (u + 0x7fffu + ((u >> 16) & 1u)) >> 16;
    return (short)r;
}

// async global->LDS, 16 B per lane; dest = lds_base (wave-uniform) + lane*16
__device__ inline void gload_lds16(const void* g, void* l) {
    auto gp = reinterpret_cast<const __attribute__((address_space(1))) void*>(
        reinterpret_cast<uintptr_t>(g));
    auto lp = reinterpret_cast<__attribute__((address_space(3))) void*>(
        reinterpret_cast<uintptr_t>(l));
    __builtin_amdgcn_global_load_lds(gp, lp, 16, 0, 0);
}

// ---------------------------------------------------------------------------
// Kernel 0: prep — Wt[n][d] = W(d,n) as bf16 (n: 0..63 Wq, 64..127 Wk, 128..191 Wv)
//           bias[192] fp32 concat
// ---------------------------------------------------------------------------
__global__ void prep_kernel(const float* __restrict__ Wq, const float* __restrict__ bq,
                            const float* __restrict__ Wk, const float* __restrict__ bk,
                            const float* __restrict__ Wv, const float* __restrict__ bv,
                            short* __restrict__ Wt, float* __restrict__ bias) {
    int idx = blockIdx.x * blockDim.x + threadIdx.x;   // 0 .. 192*1024-1
    if (idx < 192 * 1024) {
        int n = idx >> 10;
        int d = idx & 1023;
        const float* W = (n < 64) ? Wq : (n < 128) ? Wk : Wv;
        int nn = n & 63;
        Wt[idx] = f2b(W[(size_t)d * 64 + nn]);
    }
    if (idx < 192) {
        const float* bb = (idx < 64) ? bq : (idx < 128) ? bk : bv;
        bias[idx] = bb[idx & 63];
    }
}

// ---------------------------------------------------------------------------
// Kernel 1: QKV projection — LDS-staged double-buffered MFMA GEMM.
//   r11: BM 64->32, grid 512 blocks = 2 blocks/CU (was 1: the r10 profile
//   showed Occupancy 9%, 1 wave/SIMD, barrier-locked). Waves tiled 2x2:
//   wave (wr,wc) = rows wr*16..+16, col frags wc*6..+6 (96 cols).
//   LDS 2*(4KB A + 24KB B) = 56KB -> both blocks fit (112 KB/CU).
//   Staging identical to verified r10 machinery (A: reg-stage+swizzled
//   ds_write; B: global_load_lds from pre-swizzled source).
// ---------------------------------------------------------------------------
__global__ __launch_bounds__(256) void proj_kernel(const float* __restrict__ x,
        const short* __restrict__ Wt, const float* __restrict__ bias,
        short* __restrict__ Qo, short* __restrict__ Ko, short* __restrict__ Vto) {
    __shared__ short lA[2][32 * 64];    //  4 KB per buf (32 rows x 128 B)
    __shared__ short lB[2][192 * 64];   // 24 KB per buf (192 rows x 128 B)

    const int tid  = threadIdx.x;
    const int wid  = tid >> 6;
    const int lane = tid & 63;
    const int l15  = lane & 15;
    const int lg   = lane >> 4;
    const int row0 = blockIdx.x * 32;
    const int wr   = wid >> 1;          // 0..1: row half
    const int wc   = wid & 1;           // 0..1: col half

    const int sar = tid >> 4;   // 0..15: row-in-group for A staging
    const int sac = tid & 15;   // 16B chunk within 64-float k-window
    const int bn  = tid >> 3;   // 0..31: B row within round
    const int bc  = tid & 7;    // 16B chunk within 128-B B row

    f32x4 areg[2];

    auto loadA = [&](int k0) {
#pragma unroll
        for (int p = 0; p < 2; ++p) {
            int r = p * 16 + sar;
            areg[p] = *(const f32x4*)(x + (size_t)(row0 + r) * DEMB + k0 + sac * 4);
        }
    };
    auto writeA = [&](int bb) {
        char* base = (char*)lA[bb];
#pragma unroll
        for (int p = 0; p < 2; ++p) {
            int r = p * 16 + sar;
            int byte = r * 128 + ((sac * 8) ^ ((r & 7) << 4));
            s16x4 v;
            v[0] = f2b(areg[p][0]); v[1] = f2b(areg[p][1]);
            v[2] = f2b(areg[p][2]); v[3] = f2b(areg[p][3]);
            *(s16x4*)(base + byte) = v;
        }
    };
    auto stageB = [&](int k0, int bb) {
        const char* wb = (const char*)Wt;
#pragma unroll
        for (int j = 0; j < 6; ++j) {
            int n = j * 32 + bn;
            const char* src = wb + (size_t)n * 2048 + k0 * 2 + ((bc * 16) ^ ((n & 7) << 4));
            short* dst = lB[bb] + (size_t)(j * 256 + wid * 64) * 8;  // + lane*16B by HW
            gload_lds16(src, dst);
        }
    };

    f32x4 acc[6];
#pragma unroll
    for (int i = 0; i < 6; ++i) acc[i] = (f32x4){0.f, 0.f, 0.f, 0.f};

    loadA(0);
    stageB(0, 0);
    writeA(0);
    __syncthreads();

    int buf = 0;
    for (int ks = 0; ks < 16; ++ks) {
        if (ks < 15) { loadA((ks + 1) * 64); stageB((ks + 1) * 64, buf ^ 1); }

        const char* aB = (const char*)lA[buf];
        const char* bB = (const char*)lB[buf];
        const int ar = wr * 16 + l15;
        const int as = (ar & 7) << 4;
        bf16x8 a0 = *(const bf16x8*)(aB + ar * 128 + ((lg * 16) ^ as));
        bf16x8 a1 = *(const bf16x8*)(aB + ar * 128 + ((lg * 16 + 64) ^ as));
#pragma unroll
        for (int i = 0; i < 6; ++i) {
            int br = (wc * 6 + i) * 16 + l15;
            int bs = (br & 7) << 4;
            bf16x8 b0 = *(const bf16x8*)(bB + br * 128 + ((lg * 16) ^ bs));
            bf16x8 b1 = *(const bf16x8*)(bB + br * 128 + ((lg * 16 + 64) ^ bs));
            acc[i] = __builtin_amdgcn_mfma_f32_16x16x32_bf16(a0, b0, acc[i], 0, 0, 0);
            acc[i] = __builtin_amdgcn_mfma_f32_16x16x32_bf16(a1, b1, acc[i], 0, 0, 0);
        }

        if (ks < 15) writeA(buf ^ 1);
        __syncthreads();
        buf ^= 1;
    }

    // Epilogue: +bias, write bf16. C/D layout: col = l15, row = lg*4 + j.
    const int t0 = row0 + wr * 16;
#pragma unroll
    for (int i = 0; i < 6; ++i) {
        int n = (wc * 6 + i) * 16 + l15;
        float bv_ = bias[n];
#pragma unroll
        for (int j = 0; j < 4; ++j) {
            int t = t0 + lg * 4 + j;
            short v = f2b(acc[i][j] + bv_);
            if (n < 64) {
                Qo[(size_t)t * HD + n] = v;
            } else if (n < 128) {
                Ko[(size_t)t * HD + (n - 64)] = v;
            } else {
                int b = t >> 11, tt = t & 2047, d = n - 128;
                Vto[((size_t)b * HD + d) * SEQ + tt] = v;
            }
        }
    }
}

// ---------------------------------------------------------------------------
// Kernel 2: causal flash attention — LDS-staged K/V shared by 4 waves,
//   split-KV x4, KVBLK=64, double-buffered. (unchanged from passing r10)
// ---------------------------------------------------------------------------
__global__ __launch_bounds__(256, 4) void attn_kernel(const short* __restrict__ Q,
        const short* __restrict__ K, const short* __restrict__ Vt,
        float* __restrict__ Opart, float* __restrict__ mlbuf) {
    __shared__ short lK[2][64 * 64];    // 8 KB per buf
    __shared__ short lV[2][64 * 64];    // 8 KB per buf
    __shared__ short plds[4][16][72];   // per-wave P transpose (KVBLK=64 + pad)

    const int tid  = threadIdx.x;
    const int wid  = tid >> 6;
    const int lane = tid & 63;
    const int l15  = lane & 15;
    const int lg   = lane >> 4;

    const int split = blockIdx.x & 3;
    const int g0    = (blockIdx.x >> 2) & 31;
    const int b     = blockIdx.x >> 7;
    const int g     = (g0 & 1) ? (31 - (g0 >> 1)) : (g0 >> 1);
    const int q0    = g * 64 + wid * 16;      // this wave's first q row
    const int ntile = g + 1;                  // 64-wide kv tiles for this block

    const short* kbb = K  + (size_t)b * SEQ * HD;
    const short* vbb = Vt + (size_t)b * HD * SEQ;

    // staging lane decomposition: 8 rows x 8 chunks(16B) per issue
    const int srow = lane >> 3;
    const int schk = lane & 7;

    auto stageKV = [&](int kv0, int bb) {
#pragma unroll
        for (int i = 0; i < 2; ++i) {
            int rbase = wid * 16 + i * 8;
            int row   = rbase + srow;
            int swz   = (schk * 16) ^ ((row & 7) << 4);
            const char* ksrc = (const char*)(kbb + (size_t)(kv0 + row) * HD) + swz;
            const char* vsrc = (const char*)(vbb + (size_t)row * SEQ + kv0) + swz;
            gload_lds16(ksrc, &lK[bb][rbase * 64]);
            gload_lds16(vsrc, &lV[bb][rbase * 64]);
        }
    };

    // Q fragments (registers, whole kernel)
    const short* qbase = Q + ((size_t)(b * SEQ + q0 + l15)) * HD + lg * 8;
    bf16x8 qf0 = *(const bf16x8*)(qbase);
    bf16x8 qf1 = *(const bf16x8*)(qbase + 32);

    f32x4 o[4];
    float m[4], lsum[4];
#pragma unroll
    for (int df = 0; df < 4; ++df) o[df] = (f32x4){0.f, 0.f, 0.f, 0.f};
#pragma unroll
    for (int j = 0; j < 4; ++j) { m[j] = -1e30f; lsum[j] = 0.f; }

    int t = split;
    if (t < ntile) stageKV(t * 64, 0);
    __syncthreads();   // vmcnt(0) drained before barrier => staging visible

    int buf = 0;
    for (; t < ntile; t += 4) {
        if (t + 4 < ntile) stageKV((t + 4) * 64, buf ^ 1);

        const int kv0 = t * 64;
        const char* kB = (const char*)lK[buf];
        const char* vB = (const char*)lV[buf];

        // ---- S = Q K^T (4 col-frags x 2 k-steps) ----
        f32x4 s[4];
#pragma unroll
        for (int nf = 0; nf < 4; ++nf) s[nf] = (f32x4){0.f, 0.f, 0.f, 0.f};
#pragma unroll
        for (int nf = 0; nf < 4; ++nf) {
            int br = nf * 16 + l15;
            int bs = (br & 7) << 4;
            bf16x8 kf0 = *(const bf16x8*)(kB + br * 128 + ((lg * 16) ^ bs));
            bf16x8 kf1 = *(const bf16x8*)(kB + br * 128 + ((lg * 16 + 64) ^ bs));
            s[nf] = __builtin_amdgcn_mfma_f32_16x16x32_bf16(qf0, kf0, s[nf], 0, 0, 0);
            s[nf] = __builtin_amdgcn_mfma_f32_16x16x32_bf16(qf1, kf1, s[nf], 0, 0, 0);
        }

        // ---- scale + causal mask ----
        float sv[4][4];
#pragma unroll
        for (int nf = 0; nf < 4; ++nf)
#pragma unroll
            for (int j = 0; j < 4; ++j) {
                int qr = q0 + lg * 4 + j;
                int kv = kv0 + nf * 16 + l15;
                float v = s[nf][j] * 0.125f;
                sv[nf][j] = (kv <= qr) ? v : -1e30f;
            }

        // ---- row max over the 64 kv of this tile ----
        float mt[4];
#pragma unroll
        for (int j = 0; j < 4; ++j)
            mt[j] = fmaxf(fmaxf(sv[0][j], sv[1][j]), fmaxf(sv[2][j], sv[3][j]));
#pragma unroll
        for (int sh = 1; sh < 16; sh <<= 1)
#pragma unroll
            for (int j = 0; j < 4; ++j) mt[j] = fmaxf(mt[j], __shfl_xor(mt[j], sh));

        // ---- online softmax update (clamped) ----
        float p[4][4], rs[4];
#pragma unroll
        for (int j = 0; j < 4; ++j) {
            float mn = fmaxf(fmaxf(m[j], mt[j]), -1e20f);
            float sf = __expf(m[j] - mn);
            m[j] = mn;
            lsum[j] *= sf;
#pragma unroll
            for (int df = 0; df < 4; ++df) o[df][j] *= sf;
#pragma unroll
            for (int nf = 0; nf < 4; ++nf) p[nf][j] = __expf(sv[nf][j] - mn);
            rs[j] = (p[0][j] + p[1][j]) + (p[2][j] + p[3][j]);
        }
#pragma unroll
        for (int sh = 1; sh < 16; sh <<= 1)
#pragma unroll
            for (int j = 0; j < 4; ++j) rs[j] += __shfl_xor(rs[j], sh);
#pragma unroll
        for (int j = 0; j < 4; ++j) lsum[j] += rs[j];

        // ---- transpose P through LDS (per-wave buffer) ----
#pragma unroll
        for (int nf = 0; nf < 4; ++nf)
#pragma unroll
            for (int j = 0; j < 4; ++j)
                plds[wid][lg * 4 + j][nf * 16 + l15] = f2b(p[nf][j]);

        bf16x8 pa0 = *(const bf16x8*)&plds[wid][l15][lg * 8];
        bf16x8 pa1 = *(const bf16x8*)&plds[wid][l15][32 + lg * 8];

        // ---- O += P V (4 d-frags x 2 k-steps) ----
#pragma unroll
        for (int df = 0; df < 4; ++df) {
            int dr = df * 16 + l15;
            int ds = (dr & 7) << 4;
            bf16x8 vf0 = *(const bf16x8*)(vB + dr * 128 + ((lg * 16) ^ ds));
            bf16x8 vf1 = *(const bf16x8*)(vB + dr * 128 + ((lg * 16 + 64) ^ ds));
            o[df] = __builtin_amdgcn_mfma_f32_16x16x32_bf16(pa0, vf0, o[df], 0, 0, 0);
            o[df] = __builtin_amdgcn_mfma_f32_16x16x32_bf16(pa1, vf1, o[df], 0, 0, 0);
        }

        __syncthreads();   // all waves done with buf; next staging completed
        buf ^= 1;
    }

    // ---- epilogue: write unnormalized partials ----
#pragma unroll
    for (int df = 0; df < 4; ++df) {
        int d = df * 16 + l15;
#pragma unroll
        for (int j = 0; j < 4; ++j) {
            size_t R = (size_t)b * SEQ + q0 + lg * 4 + j;
            Opart[((size_t)split * NROWS + R) * HD + d] = o[df][j];
        }
    }
    if (l15 == 0) {
#pragma unroll
        for (int j = 0; j < 4; ++j) {
            size_t R = (size_t)b * SEQ + q0 + lg * 4 + j;
            mlbuf[((size_t)split * NROWS + R) * 2 + 0] = m[j];
            mlbuf[((size_t)split * NROWS + R) * 2 + 1] = lsum[j];
        }
    }
}

// ---------------------------------------------------------------------------
// Kernel 3: merge 4 KV-split partials -> normalized output.
// ---------------------------------------------------------------------------
__global__ __launch_bounds__(256) void merge_kernel(const float* __restrict__ Opart,
        const float* __restrict__ mlbuf, float* __restrict__ out) {
    int tg = blockIdx.x * 256 + threadIdx.x;   // 0 .. 262143
    int rr = tg >> 4;
    int fc = tg & 15;

    float mv[4], lv[4];
    float M = -3e38f;
#pragma unroll
    for (int i = 0; i < 4; ++i) {
        mv[i] = mlbuf[((size_t)i * NROWS + rr) * 2 + 0];
        lv[i] = mlbuf[((size_t)i * NROWS + rr) * 2 + 1];
        M = fmaxf(M, mv[i]);
    }
    float L = 0.f;
    f32x4 acc = (f32x4){0.f, 0.f, 0.f, 0.f};
#pragma unroll
    for (int i = 0; i < 4; ++i) {
        float w = __expf(mv[i] - M);
        L += lv[i] * w;
        f32x4 v = *(const f32x4*)(Opart + ((size_t)i * NROWS + rr) * HD + fc * 4);
        acc += v * w;
    }
    f32x4 r = acc / L;
    *(f32x4*)(out + (size_t)rr * HD + fc * 4) = r;
}

// ---------------------------------------------------------------------------
extern "C" void kernel_launch(void* const* d_in, const int* in_sizes, int n_in,
                              void* d_out, int out_size, void* d_ws, size_t ws_size,
                              hipStream_t stream) {
    const float* x  = (const float*)d_in[0];
    const float* Wq = (const float*)d_in[1];
    const float* bq = (const float*)d_in[2];
    const float* Wk = (const float*)d_in[3];
    const float* bk = (const float*)d_in[4];
    const float* Wv = (const float*)d_in[5];
    const float* bv = (const float*)d_in[6];
    float* out = (float*)d_out;

    char* ws = (char*)d_ws;
    // Workspace layout (bytes):
    //   Wt    bf16 [192][1024]        @ 0         (393216)
    //   bias  f32  [192]              @ 393216    (768, pad to 394240)
    //   Q     bf16 [16384][64]        @ 394240    (2097152)
    //   K     bf16 [16384][64]        @ 2491392   (2097152)
    //   Vt    bf16 [8][64][2048]      @ 4588544   (2097152)
    //   Opart f32  [4][16384][64]     @ 6685696   (16777216)
    //   ml    f32  [4][16384][2]      @ 23462912  (524288)   end 23987200
    short* Wt   = (short*)(ws);
    float* bias = (float*)(ws + 393216);
    short* Qb   = (short*)(ws + 394240);
    short* Kb   = (short*)(ws + 394240 + 2097152);
    short* Vtb  = (short*)(ws + 394240 + 2 * 2097152);
    float* Op   = (float*)(ws + 6685696);
    float* ml   = (float*)(ws + 23462912);

    hipLaunchKernelGGL(prep_kernel, dim3(768), dim3(256), 0, stream,
                       Wq, bq, Wk, bk, Wv, bv, Wt, bias);
    hipLaunchKernelGGL(proj_kernel, dim3(512), dim3(256), 0, stream,
                       x, Wt, bias, Qb, Kb, Vtb);
    hipLaunchKernelGGL(attn_kernel, dim3(1024), dim3(256), 0, stream,
                       Qb, Kb, Vtb, Op, ml);
    hipLaunchKernelGGL(merge_kernel, dim3(1024), dim3(256), 0, stream,
                       Op, ml, out);
}

// Round 12
// 61.743 us; speedup vs baseline: 2.5678x; 1.1202x over previous
//
#include <hip/hip_runtime.h>
#include <hip/hip_bf16.h>
#include <stdint.h>

// Problem constants
#define BATCH 8
#define SEQ   2048
#define DEMB  1024
#define HD    64
#define NROWS (BATCH * SEQ)   // 16384

typedef __attribute__((ext_vector_type(8))) short bf16x8;  // 8 bf16 in 4 VGPRs
typedef __attribute__((ext_vector_type(4))) short s16x4;   // 4 bf16 (8 B)
typedef __attribute__((ext_vector_type(4))) float f32x4;

// fp32 -> bf16 round-to-nearest-even (bit pattern as short)
__device__ inline short f2b(float f) {
    unsigned u = __builtin_bit_cast(unsigned, f);
    unsigned r = (u + 0x7fffu + ((u >> 16) & 1u)) >> 16;
    return (short)r;
}
// native cast path (lets the compiler fuse pairs into v_cvt_pk_bf16_f32)
__device__ inline short f2bn(float f) {
    __hip_bfloat16 h(f);
    return __builtin_bit_cast(short, h);
}

// async global->LDS, 16 B per lane; dest = lds_base (wave-uniform) + lane*16
__device__ inline void gload_lds16(const void* g, void* l) {
    auto gp = reinterpret_cast<const __attribute__((address_space(1))) void*>(
        reinterpret_cast<uintptr_t>(g));
    auto lp = reinterpret_cast<__attribute__((address_space(3))) void*>(
        reinterpret_cast<uintptr_t>(l));
    __builtin_amdgcn_global_load_lds(gp, lp, 16, 0, 0);
}

// ---------------------------------------------------------------------------
// Kernel 0: prep — Wt[n][d] = W(d,n) as bf16 (n: 0..63 Wq, 64..127 Wk, 128..191 Wv)
//           bias[192] fp32 concat
// ---------------------------------------------------------------------------
__global__ void prep_kernel(const float* __restrict__ Wq, const float* __restrict__ bq,
                            const float* __restrict__ Wk, const float* __restrict__ bk,
                            const float* __restrict__ Wv, const float* __restrict__ bv,
                            short* __restrict__ Wt, float* __restrict__ bias) {
    int idx = blockIdx.x * blockDim.x + threadIdx.x;   // 0 .. 192*1024-1
    if (idx < 192 * 1024) {
        int n = idx >> 10;
        int d = idx & 1023;
        const float* W = (n < 64) ? Wq : (n < 128) ? Wk : Wv;
        int nn = n & 63;
        Wt[idx] = f2b(W[(size_t)d * 64 + nn]);
    }
    if (idx < 192) {
        const float* bb = (idx < 64) ? bq : (idx < 128) ? bk : bv;
        bias[idx] = bb[idx & 63];
    }
}

// ---------------------------------------------------------------------------
// Kernel 1: QKV projection — LDS-staged double-buffered MFMA GEMM (r11, passing).
//   512 blocks (2/CU), BM=32, waves 2x2, 56KB LDS.
// ---------------------------------------------------------------------------
__global__ __launch_bounds__(256) void proj_kernel(const float* __restrict__ x,
        const short* __restrict__ Wt, const float* __restrict__ bias,
        short* __restrict__ Qo, short* __restrict__ Ko, short* __restrict__ Vto) {
    __shared__ short lA[2][32 * 64];    //  4 KB per buf (32 rows x 128 B)
    __shared__ short lB[2][192 * 64];   // 24 KB per buf (192 rows x 128 B)

    const int tid  = threadIdx.x;
    const int wid  = tid >> 6;
    const int lane = tid & 63;
    const int l15  = lane & 15;
    const int lg   = lane >> 4;
    const int row0 = blockIdx.x * 32;
    const int wr   = wid >> 1;          // 0..1: row half
    const int wc   = wid & 1;           // 0..1: col half

    const int sar = tid >> 4;   // 0..15: row-in-group for A staging
    const int sac = tid & 15;   // 16B chunk within 64-float k-window
    const int bn  = tid >> 3;   // 0..31: B row within round
    const int bc  = tid & 7;    // 16B chunk within 128-B B row

    f32x4 areg[2];

    auto loadA = [&](int k0) {
#pragma unroll
        for (int p = 0; p < 2; ++p) {
            int r = p * 16 + sar;
            areg[p] = *(const f32x4*)(x + (size_t)(row0 + r) * DEMB + k0 + sac * 4);
        }
    };
    auto writeA = [&](int bb) {
        char* base = (char*)lA[bb];
#pragma unroll
        for (int p = 0; p < 2; ++p) {
            int r = p * 16 + sar;
            int byte = r * 128 + ((sac * 8) ^ ((r & 7) << 4));
            s16x4 v;
            v[0] = f2b(areg[p][0]); v[1] = f2b(areg[p][1]);
            v[2] = f2b(areg[p][2]); v[3] = f2b(areg[p][3]);
            *(s16x4*)(base + byte) = v;
        }
    };
    auto stageB = [&](int k0, int bb) {
        const char* wb = (const char*)Wt;
#pragma unroll
        for (int j = 0; j < 6; ++j) {
            int n = j * 32 + bn;
            const char* src = wb + (size_t)n * 2048 + k0 * 2 + ((bc * 16) ^ ((n & 7) << 4));
            short* dst = lB[bb] + (size_t)(j * 256 + wid * 64) * 8;  // + lane*16B by HW
            gload_lds16(src, dst);
        }
    };

    f32x4 acc[6];
#pragma unroll
    for (int i = 0; i < 6; ++i) acc[i] = (f32x4){0.f, 0.f, 0.f, 0.f};

    loadA(0);
    stageB(0, 0);
    writeA(0);
    __syncthreads();

    int buf = 0;
    for (int ks = 0; ks < 16; ++ks) {
        if (ks < 15) { loadA((ks + 1) * 64); stageB((ks + 1) * 64, buf ^ 1); }

        const char* aB = (const char*)lA[buf];
        const char* bB = (const char*)lB[buf];
        const int ar = wr * 16 + l15;
        const int as = (ar & 7) << 4;
        bf16x8 a0 = *(const bf16x8*)(aB + ar * 128 + ((lg * 16) ^ as));
        bf16x8 a1 = *(const bf16x8*)(aB + ar * 128 + ((lg * 16 + 64) ^ as));
#pragma unroll
        for (int i = 0; i < 6; ++i) {
            int br = (wc * 6 + i) * 16 + l15;
            int bs = (br & 7) << 4;
            bf16x8 b0 = *(const bf16x8*)(bB + br * 128 + ((lg * 16) ^ bs));
            bf16x8 b1 = *(const bf16x8*)(bB + br * 128 + ((lg * 16 + 64) ^ bs));
            acc[i] = __builtin_amdgcn_mfma_f32_16x16x32_bf16(a0, b0, acc[i], 0, 0, 0);
            acc[i] = __builtin_amdgcn_mfma_f32_16x16x32_bf16(a1, b1, acc[i], 0, 0, 0);
        }

        if (ks < 15) writeA(buf ^ 1);
        __syncthreads();
        buf ^= 1;
    }

    // Epilogue: +bias, write bf16. C/D layout: col = l15, row = lg*4 + j.
    const int t0 = row0 + wr * 16;
#pragma unroll
    for (int i = 0; i < 6; ++i) {
        int n = (wc * 6 + i) * 16 + l15;
        float bv_ = bias[n];
#pragma unroll
        for (int j = 0; j < 4; ++j) {
            int t = t0 + lg * 4 + j;
            short v = f2b(acc[i][j] + bv_);
            if (n < 64) {
                Qo[(size_t)t * HD + n] = v;
            } else if (n < 128) {
                Ko[(size_t)t * HD + (n - 64)] = v;
            } else {
                int b = t >> 11, tt = t & 2047, d = n - 128;
                Vto[((size_t)b * HD + d) * SEQ + tt] = v;
            }
        }
    }
}

// ---------------------------------------------------------------------------
// Kernel 2: causal flash attention — r12: UNIFORM WORK via g<->31-g pairing.
//   Grid: 8 b x 16 pairs x 4 split = 512 blocks x 4 waves.
//   Block (b,p,s) processes chunk g=p then g=31-p, tiles t = s, s+4, ...
//   Per-block tiles = 8 or 9 for EVERY block (r11's 0..8 imbalance caused the
//   14% decaying occupancy). Each chunk: fresh online-softmax state, K/V tiles
//   (KVBLK=64) staged once/block via global_load_lds (pre-swizzled source),
//   double-buffered, shared by 4 waves. exp2-folded softmax (scale*log2e).
//   Unnormalized partials + (m,l) per split -> merge.
// ---------------------------------------------------------------------------
__global__ __launch_bounds__(256, 4) void attn_kernel(const short* __restrict__ Q,
        const short* __restrict__ K, const short* __restrict__ Vt,
        float* __restrict__ Opart, float* __restrict__ mlbuf) {
    __shared__ short lK[2][64 * 64];    // 8 KB per buf
    __shared__ short lV[2][64 * 64];    // 8 KB per buf
    __shared__ short plds[4][16][72];   // per-wave P transpose (KVBLK=64 + pad)

    const int tid  = threadIdx.x;
    const int wid  = tid >> 6;
    const int lane = tid & 63;
    const int l15  = lane & 15;
    const int lg   = lane >> 4;

    const int split = blockIdx.x & 3;
    const int pr    = (blockIdx.x >> 2) & 15;
    const int b     = blockIdx.x >> 6;

    const short* kbb = K  + (size_t)b * SEQ * HD;
    const short* vbb = Vt + (size_t)b * HD * SEQ;

    // staging lane decomposition: 8 rows x 8 chunks(16B) per issue
    const int srow = lane >> 3;
    const int schk = lane & 7;

    auto stageKV = [&](int kv0, int bb) {
#pragma unroll
        for (int i = 0; i < 2; ++i) {
            int rbase = wid * 16 + i * 8;
            int row   = rbase + srow;
            int swz   = (schk * 16) ^ ((row & 7) << 4);
            const char* ksrc = (const char*)(kbb + (size_t)(kv0 + row) * HD) + swz;
            const char* vsrc = (const char*)(vbb + (size_t)row * SEQ + kv0) + swz;
            gload_lds16(ksrc, &lK[bb][rbase * 64]);
            gload_lds16(vsrc, &lV[bb][rbase * 64]);
        }
    };

    const float SC = 0.18033688f;   // 0.125 * log2(e): softmax in base-2 domain

    for (int ci = 0; ci < 2; ++ci) {
        const int g     = ci ? (31 - pr) : pr;
        const int q0    = g * 64 + wid * 16;   // this wave's first q row
        const int ntile = g + 1;               // 64-wide kv tiles for this chunk

        // Q fragments for this chunk
        const short* qbase = Q + ((size_t)(b * SEQ + q0 + l15)) * HD + lg * 8;
        bf16x8 qf0 = *(const bf16x8*)(qbase);
        bf16x8 qf1 = *(const bf16x8*)(qbase + 32);

        f32x4 o[4];
        float m[4], lsum[4];
#pragma unroll
        for (int df = 0; df < 4; ++df) o[df] = (f32x4){0.f, 0.f, 0.f, 0.f};
#pragma unroll
        for (int j = 0; j < 4; ++j) { m[j] = -1e30f; lsum[j] = 0.f; }

        int t = split;
        if (t < ntile) stageKV(t * 64, 0);
        __syncthreads();   // vmcnt(0) drained before barrier => staging visible

        int buf = 0;
        for (; t < ntile; t += 4) {
            if (t + 4 < ntile) stageKV((t + 4) * 64, buf ^ 1);

            const int kv0 = t * 64;
            const char* kB = (const char*)lK[buf];
            const char* vB = (const char*)lV[buf];

            // ---- S = Q K^T (4 col-frags x 2 k-steps) ----
            f32x4 s[4];
#pragma unroll
            for (int nf = 0; nf < 4; ++nf) s[nf] = (f32x4){0.f, 0.f, 0.f, 0.f};
#pragma unroll
            for (int nf = 0; nf < 4; ++nf) {
                int br = nf * 16 + l15;
                int bs = (br & 7) << 4;
                bf16x8 kf0 = *(const bf16x8*)(kB + br * 128 + ((lg * 16) ^ bs));
                bf16x8 kf1 = *(const bf16x8*)(kB + br * 128 + ((lg * 16 + 64) ^ bs));
                s[nf] = __builtin_amdgcn_mfma_f32_16x16x32_bf16(qf0, kf0, s[nf], 0, 0, 0);
                s[nf] = __builtin_amdgcn_mfma_f32_16x16x32_bf16(qf1, kf1, s[nf], 0, 0, 0);
            }

            // ---- scale (base-2 folded) + causal mask ----
            float sv[4][4];
#pragma unroll
            for (int nf = 0; nf < 4; ++nf)
#pragma unroll
                for (int j = 0; j < 4; ++j) {
                    int qr = q0 + lg * 4 + j;
                    int kv = kv0 + nf * 16 + l15;
                    float v = s[nf][j] * SC;
                    sv[nf][j] = (kv <= qr) ? v : -1e30f;
                }

            // ---- row max over the 64 kv of this tile ----
            float mt[4];
#pragma unroll
            for (int j = 0; j < 4; ++j)
                mt[j] = fmaxf(fmaxf(sv[0][j], sv[1][j]), fmaxf(sv[2][j], sv[3][j]));
#pragma unroll
            for (int sh = 1; sh < 16; sh <<= 1)
#pragma unroll
                for (int j = 0; j < 4; ++j) mt[j] = fmaxf(mt[j], __shfl_xor(mt[j], sh));

            // ---- online softmax update (exp2 domain, clamped) ----
            float p[4][4], rs[4];
#pragma unroll
            for (int j = 0; j < 4; ++j) {
                float mn = fmaxf(fmaxf(m[j], mt[j]), -1e20f);
                float sf = exp2f(m[j] - mn);
                m[j] = mn;
                lsum[j] *= sf;
#pragma unroll
                for (int df = 0; df < 4; ++df) o[df][j] *= sf;
#pragma unroll
                for (int nf = 0; nf < 4; ++nf) p[nf][j] = exp2f(sv[nf][j] - mn);
                rs[j] = (p[0][j] + p[1][j]) + (p[2][j] + p[3][j]);
            }
#pragma unroll
            for (int sh = 1; sh < 16; sh <<= 1)
#pragma unroll
                for (int j = 0; j < 4; ++j) rs[j] += __shfl_xor(rs[j], sh);
#pragma unroll
            for (int j = 0; j < 4; ++j) lsum[j] += rs[j];

            // ---- transpose P through LDS (per-wave buffer) ----
#pragma unroll
            for (int nf = 0; nf < 4; ++nf)
#pragma unroll
                for (int j = 0; j < 4; ++j)
                    plds[wid][lg * 4 + j][nf * 16 + l15] = f2bn(p[nf][j]);

            bf16x8 pa0 = *(const bf16x8*)&plds[wid][l15][lg * 8];
            bf16x8 pa1 = *(const bf16x8*)&plds[wid][l15][32 + lg * 8];

            // ---- O += P V (4 d-frags x 2 k-steps) ----
#pragma unroll
            for (int df = 0; df < 4; ++df) {
                int dr = df * 16 + l15;
                int ds = (dr & 7) << 4;
                bf16x8 vf0 = *(const bf16x8*)(vB + dr * 128 + ((lg * 16) ^ ds));
                bf16x8 vf1 = *(const bf16x8*)(vB + dr * 128 + ((lg * 16 + 64) ^ ds));
                o[df] = __builtin_amdgcn_mfma_f32_16x16x32_bf16(pa0, vf0, o[df], 0, 0, 0);
                o[df] = __builtin_amdgcn_mfma_f32_16x16x32_bf16(pa1, vf1, o[df], 0, 0, 0);
            }

            __syncthreads();   // all waves done with buf; next staging completed
            buf ^= 1;
        }

        // ---- epilogue: write unnormalized partials for this chunk ----
#pragma unroll
        for (int df = 0; df < 4; ++df) {
            int d = df * 16 + l15;
#pragma unroll
            for (int j = 0; j < 4; ++j) {
                size_t R = (size_t)b * SEQ + q0 + lg * 4 + j;
                Opart[((size_t)split * NROWS + R) * HD + d] = o[df][j];
            }
        }
        if (l15 == 0) {
#pragma unroll
            for (int j = 0; j < 4; ++j) {
                size_t R = (size_t)b * SEQ + q0 + lg * 4 + j;
                mlbuf[((size_t)split * NROWS + R) * 2 + 0] = m[j];
                mlbuf[((size_t)split * NROWS + R) * 2 + 1] = lsum[j];
            }
        }
    }
}

// ---------------------------------------------------------------------------
// Kernel 3: merge 4 KV-split partials -> normalized output (exp2 domain).
// ---------------------------------------------------------------------------
__global__ __launch_bounds__(256) void merge_kernel(const float* __restrict__ Opart,
        const float* __restrict__ mlbuf, float* __restrict__ out) {
    int tg = blockIdx.x * 256 + threadIdx.x;   // 0 .. 262143
    int rr = tg >> 4;
    int fc = tg & 15;

    float mv[4], lv[4];
    float M = -3e38f;
#pragma unroll
    for (int i = 0; i < 4; ++i) {
        mv[i] = mlbuf[((size_t)i * NROWS + rr) * 2 + 0];
        lv[i] = mlbuf[((size_t)i * NROWS + rr) * 2 + 1];
        M = fmaxf(M, mv[i]);
    }
    float L = 0.f;
    f32x4 acc = (f32x4){0.f, 0.f, 0.f, 0.f};
#pragma unroll
    for (int i = 0; i < 4; ++i) {
        float w = exp2f(mv[i] - M);
        L += lv[i] * w;
        f32x4 v = *(const f32x4*)(Opart + ((size_t)i * NROWS + rr) * HD + fc * 4);
        acc += v * w;
    }
    f32x4 r = acc / L;
    *(f32x4*)(out + (size_t)rr * HD + fc * 4) = r;
}

// ---------------------------------------------------------------------------
extern "C" void kernel_launch(void* const* d_in, const int* in_sizes, int n_in,
                              void* d_out, int out_size, void* d_ws, size_t ws_size,
                              hipStream_t stream) {
    const float* x  = (const float*)d_in[0];
    const float* Wq = (const float*)d_in[1];
    const float* bq = (const float*)d_in[2];
    const float* Wk = (const float*)d_in[3];
    const float* bk = (const float*)d_in[4];
    const float* Wv = (const float*)d_in[5];
    const float* bv = (const float*)d_in[6];
    float* out = (float*)d_out;

    char* ws = (char*)d_ws;
    // Workspace layout (bytes):
    //   Wt    bf16 [192][1024]        @ 0         (393216)
    //   bias  f32  [192]              @ 393216    (768, pad to 394240)
    //   Q     bf16 [16384][64]        @ 394240    (2097152)
    //   K     bf16 [16384][64]        @ 2491392   (2097152)
    //   Vt    bf16 [8][64][2048]      @ 4588544   (2097152)
    //   Opart f32  [4][16384][64]     @ 6685696   (16777216)
    //   ml    f32  [4][16384][2]      @ 23462912  (524288)   end 23987200
    short* Wt   = (short*)(ws);
    float* bias = (float*)(ws + 393216);
    short* Qb   = (short*)(ws + 394240);
    short* Kb   = (short*)(ws + 394240 + 2097152);
    short* Vtb  = (short*)(ws + 394240 + 2 * 2097152);
    float* Op   = (float*)(ws + 6685696);
    float* ml   = (float*)(ws + 23462912);

    hipLaunchKernelGGL(prep_kernel, dim3(768), dim3(256), 0, stream,
                       Wq, bq, Wk, bk, Wv, bv, Wt, bias);
    hipLaunchKernelGGL(proj_kernel, dim3(512), dim3(256), 0, stream,
                       x, Wt, bias, Qb, Kb, Vtb);
    hipLaunchKernelGGL(attn_kernel, dim3(512), dim3(256), 0, stream,
                       Qb, Kb, Vtb, Op, ml);
    hipLaunchKernelGGL(merge_kernel, dim3(1024), dim3(256), 0, stream,
                       Op, ml, out);
}